// Round 7
// baseline (254.476 us; speedup 1.0000x reference)
//
#include <hip/hip_runtime.h>

#define NIMG 4
#define NCLS 19
#define CCH  32
#define LH   128
#define LW   128
#define HH   512
#define WW   512
#define HWQ  (LH*LW)    // 16384 low-res pixels
#define HWP  (HH*WW)    // 262144 hi-res pixels

// k_b tiling: each block OWNS a disjoint TRxTC low-res region
#define TR 8
#define TC 8
#define NTX 16            // LW/TC
#define NTILE 256         // tiles per image -> 1024 blocks total
#define TCELLS 64         // TR*TC
#define RW 10             // halo quad-cols (X0-1 .. X0+8)
#define HITEMS 360        // (TR*4+4)*RW
#define NSLOT 608         // NCLS*CCH
#define NBAND 64          // k_a bands per image (8 hi-res rows each)

// Bilinear taps for 128 -> 512, half-pixel convention. Edge taps shifted to a
// valid (b, b+1) pair with weights {1,0}/{0,1} (exact dyadic, same math).
__device__ __forceinline__ void taps(int v, int lim, int& i0, float& w0, float& w1) {
    int r = v & 3;
    int b = (v >> 2) + ((r < 2) ? -1 : 0);
    float f = 0.125f + 0.25f * (float)((r + 2) & 3);   // r: 0->.625 1->.875 2->.125 3->.375
    w0 = 1.f - f; w1 = f;
    if (b < 0)           { b = 0;       w0 = 1.f; w1 = 0.f; }
    else if (b >= lim)   { b = lim - 1; w0 = 0.f; w1 = 1.f; }
    i0 = b;
}

// K_A: per-band fused Gram+S2. Block (rp,n) computes Gram rows 2rp..2rp+2 in
// LDS (planes: self,h,v,diag+anti) from coalesced E rows, then evaluates
// ||v_p||^2 for hi-res rows [8rp+2, 8rp+10) (rp=0 also rows 0,1) with
// coalesced int4 label loads. Writes P_S2[n][rp][19]. Zeroes Cnt.
__global__ __launch_bounds__(512) void k_a(const float* __restrict__ E,
        const int* __restrict__ lab, float* __restrict__ P_S2,
        unsigned int* __restrict__ Cnt) {
    int rp = blockIdx.x, n = blockIdx.y;
    int tid = threadIdx.x;
    int x = tid & 127, quarter = tid >> 7;      // 4-way channel split, 8 ch each
    __shared__ float Gt[4 * 3 * 128];           // [plane][row j][x]  6 KB
    __shared__ float S2w[32 * NCLS];            // 32-copy S2 accumulators
    if (rp == 0 && n == 0 && tid < NIMG) Cnt[tid] = 0u;
    for (int i = tid; i < 4 * 3 * 128; i += 512) Gt[i] = 0.f;
    for (int i = tid; i < 32 * NCLS; i += 512) S2w[i] = 0.f;

    int y0r = 2 * rp;
    int yr[4];
#pragma unroll
    for (int j = 0; j < 4; j++) { int y = y0r + j; yr[j] = y > LH - 1 ? LH - 1 : y; }
    int xn = x < LW - 1 ? x + 1 : LW - 1;
    bool fix = ((x & 63) == 63);                // wave edge: shfl_down(1) invalid
    const float* Eb = E + (size_t)(n * CCH + quarter * 8) * HWQ;
    float gs0=0,gs1=0,gs2=0, gh0=0,gh1=0,gh2=0, gv0=0,gv1=0,gv2=0, gd0=0,gd1=0,gd2=0;
    __syncthreads();                            // Gt zero visible before atomics
#pragma unroll 4
    for (int ci = 0; ci < 8; ci++) {
        const float* Ec = Eb + (size_t)ci * HWQ;
        float r0 = Ec[yr[0] * LW + x];
        float r1 = Ec[yr[1] * LW + x];
        float r2 = Ec[yr[2] * LW + x];
        float r3 = Ec[yr[3] * LW + x];
        float s0 = __shfl_down(r0, 1), s1 = __shfl_down(r1, 1);
        float s2 = __shfl_down(r2, 1), s3 = __shfl_down(r3, 1);
        if (fix) { s0 = Ec[yr[0] * LW + xn]; s1 = Ec[yr[1] * LW + xn];
                   s2 = Ec[yr[2] * LW + xn]; s3 = Ec[yr[3] * LW + xn]; }
        gs0 = fmaf(r0, r0, gs0); gh0 = fmaf(r0, s0, gh0);
        gv0 = fmaf(r0, r1, gv0); gd0 = fmaf(r0, s1, fmaf(s0, r1, gd0));
        gs1 = fmaf(r1, r1, gs1); gh1 = fmaf(r1, s1, gh1);
        gv1 = fmaf(r1, r2, gv1); gd1 = fmaf(r1, s2, fmaf(s1, r2, gd1));
        gs2 = fmaf(r2, r2, gs2); gh2 = fmaf(r2, s2, gh2);
        gv2 = fmaf(r2, r3, gv2); gd2 = fmaf(r2, s3, fmaf(s2, r3, gd2));
    }
    atomicAdd(&Gt[0 * 384 + 0 * 128 + x], gs0);
    atomicAdd(&Gt[0 * 384 + 1 * 128 + x], gs1);
    atomicAdd(&Gt[0 * 384 + 2 * 128 + x], gs2);
    atomicAdd(&Gt[1 * 384 + 0 * 128 + x], gh0);
    atomicAdd(&Gt[1 * 384 + 1 * 128 + x], gh1);
    atomicAdd(&Gt[1 * 384 + 2 * 128 + x], gh2);
    atomicAdd(&Gt[2 * 384 + 0 * 128 + x], gv0);
    atomicAdd(&Gt[2 * 384 + 1 * 128 + x], gv1);
    atomicAdd(&Gt[2 * 384 + 2 * 128 + x], gv2);
    atomicAdd(&Gt[3 * 384 + 0 * 128 + x], gd0);
    atomicAdd(&Gt[3 * 384 + 1 * 128 + x], gd1);
    atomicAdd(&Gt[3 * 384 + 2 * 128 + x], gd2);
    __syncthreads();

    // ---- S2 over the band: one thread per 4-pixel quad-row ----
    const float* Gs_ = Gt, *Gh_ = Gt + 384, *Gv_ = Gt + 768, *Gda_ = Gt + 1152;
    int h_start = (rp == 0) ? 0 : 8 * rp + 2;
    int h_end = 8 * rp + 10; if (h_end > HH) h_end = HH;
    int nItems = (h_end - h_start) * 128;
    const int* ln = lab + (size_t)n * HWP;
    for (int it = tid; it < nItems; it += 512) {
        int h = h_start + (it >> 7), q = it & 127;
        int y0; float wy0, wy1;
        taps(h, LH - 1, y0, wy0, wy1);
        int jj = y0 - y0r;                      // 0 or 1 by construction
        int4 l4 = *(const int4*)(ln + h * WW + (q << 2));
        float u0 = wy0 * wy0, u1 = wy1 * wy1, u2t = 2.f * wy0 * wy1;
        int b0 = jj * 128, b1 = b0 + 128;
        int wv = (tid >> 4) * NCLS;
        if (q >= 1 && q <= 126) {
            int xm = q - 1;
            float C0 = u0 * Gs_[b0 + xm]    + u1 * Gs_[b1 + xm]    + u2t * Gv_[b0 + xm];
            float C1 = u0 * Gs_[b0 + q]     + u1 * Gs_[b1 + q]     + u2t * Gv_[b0 + q];
            float C2 = u0 * Gs_[b0 + q + 1] + u1 * Gs_[b1 + q + 1] + u2t * Gv_[b0 + q + 1];
            float D0 = 2.f * (u0 * Gh_[b0 + xm] + u1 * Gh_[b1 + xm]) + u2t * Gda_[b0 + xm];
            float D1 = 2.f * (u0 * Gh_[b0 + q]  + u1 * Gh_[b1 + q])  + u2t * Gda_[b0 + q];
            float d2a = fmaf(0.140625f, C0, fmaf(0.390625f, C1, 0.234375f * D0));
            float d2b = fmaf(0.015625f, C0, fmaf(0.765625f, C1, 0.109375f * D0));
            float d2c = fmaf(0.765625f, C1, fmaf(0.015625f, C2, 0.109375f * D1));
            float d2d = fmaf(0.390625f, C1, fmaf(0.140625f, C2, 0.234375f * D1));
            atomicAdd(&S2w[wv + l4.x], d2a); atomicAdd(&S2w[wv + l4.y], d2b);
            atomicAdd(&S2w[wv + l4.z], d2c); atomicAdd(&S2w[wv + l4.w], d2d);
        } else {
            int Ls[4] = {l4.x, l4.y, l4.z, l4.w};
#pragma unroll
            for (int j2 = 0; j2 < 4; j2++) {
                int w = (q << 2) + j2;
                int x0; float wx0, wx1;
                taps(w, LW - 1, x0, wx0, wx1);
                float Ca = u0 * Gs_[b0 + x0]     + u1 * Gs_[b1 + x0]     + u2t * Gv_[b0 + x0];
                float Cb = u0 * Gs_[b0 + x0 + 1] + u1 * Gs_[b1 + x0 + 1] + u2t * Gv_[b0 + x0 + 1];
                float Dd = 2.f * (u0 * Gh_[b0 + x0] + u1 * Gh_[b1 + x0]) + u2t * Gda_[b0 + x0];
                float d2 = wx0 * wx0 * Ca + wx1 * wx1 * Cb + wx0 * wx1 * Dd;
                atomicAdd(&S2w[wv + Ls[j2]], d2);
            }
        }
    }
    __syncthreads();
    if (tid < NCLS) {
        float s = 0.f;
#pragma unroll
        for (int j = 0; j < 32; j++) s += S2w[j * NCLS + tid];
        P_S2[(size_t)(n * NBAND + rp) * NCLS + tid] = s;
    }
}

// K_B: per-tile A-field halo + contract -> plain coalesced stores; last block
// per image (device ticket) reduces all partials in f64 and writes out[n].
__global__ __launch_bounds__(256, 6) void k_b(const float* __restrict__ E,
        const int* __restrict__ lab, float* __restrict__ P_sum,
        float* __restrict__ P_cnt, const float* __restrict__ P_S2,
        unsigned int* __restrict__ Cnt, float* __restrict__ out) {
    int tile = blockIdx.x, n = blockIdx.y;
    int ty = tile >> 4, tx = tile & 15;         // NTX=16
    int Y0 = ty * TR, X0 = tx * TC;
    __shared__ float A[NCLS * TCELLS];          // 4864 B [k][cell]
    __shared__ float tmpc[NCLS * 8];
    __shared__ __align__(16) float cs_l[NSLOT];
    __shared__ unsigned int sdone;
    __shared__ double cs_d[NCLS * 33];
    __shared__ double m_d[NCLS * 33];
    __shared__ double cnt_d[NCLS], s2_d[NCLS];
    __shared__ double rk1[NCLS * 9];
    __shared__ double rk2[NCLS * 5];
    __shared__ double wpart[4];
    __shared__ double sIntra, sNfg;
    int tid = threadIdx.x;
    const int* ln = lab + (size_t)n * HWP;
    int h_lo = Y0 * 4 - 2;

    // ---- hoisted cold loads: 2x lab int4, E 2x float4 ----
    int hA = h_lo + tid / RW, qA = X0 - 1 + tid % RW;
    int4 LA;
    {
        int hc = hA < 0 ? 0 : (hA > HH - 1 ? HH - 1 : hA);
        int qc = qA < 0 ? 0 : (qA > LW - 1 ? LW - 1 : qA);
        LA = *(const int4*)(ln + hc * WW + (qc << 2));
    }
    bool vB = tid < (HITEMS - 256);
    int hB = 0, qB = 0; int4 LB = make_int4(0, 0, 0, 0);
    if (vB) {
        int i = tid + 256;
        hB = h_lo + i / RW; qB = X0 - 1 + i % RW;
        int hc = hB < 0 ? 0 : (hB > HH - 1 ? HH - 1 : hB);
        int qc = qB < 0 ? 0 : (qB > LW - 1 ? LW - 1 : qB);
        LB = *(const int4*)(ln + hc * WW + (qc << 2));
    }
    int cc = tid >> 3, cy = tid & 7;
    const float* Er = E + (size_t)(n * CCH + cc) * HWQ + (Y0 + cy) * LW + X0;
    float4 ev0 = ((const float4*)Er)[0];
    float4 ev1 = ((const float4*)Er)[1];

    for (int i = tid; i < NCLS * TCELLS; i += 256) A[i] = 0.f;
    __syncthreads();

    // ---- halo pass (A taps only) ----
    auto process = [&](int h, int q, int4 l4) {
        if (h < 0 || h >= HH || q < 0 || q >= LW) return;
        int y0; float wy0, wy1;
        taps(h, LH - 1, y0, wy0, wy1);
        int ry = y0 - Y0;
        bool r0 = (unsigned)ry < (unsigned)TR, r1 = (unsigned)(ry + 1) < (unsigned)TR;
        int rxm = q - 1 - X0, rx0 = q - X0, rxp = q + 1 - X0;
        bool bm = (unsigned)rxm < (unsigned)TC, b0 = (unsigned)rx0 < (unsigned)TC,
             bp = (unsigned)rxp < (unsigned)TC;
        if (q >= 1 && q <= 126) {
            // x-weights: p0:(q-1:.375,q:.625) p1:(.125,.875) p2:(q:.875,q+1:.125) p3:(.625,.375)
            if (r0) {
                int rb = ry * TC;
                if (bm) { float* a = &A[rb + rxm];
                    atomicAdd(a + l4.x * TCELLS, wy0 * 0.375f); atomicAdd(a + l4.y * TCELLS, wy0 * 0.125f); }
                if (b0) { float* a = &A[rb + rx0];
                    atomicAdd(a + l4.x * TCELLS, wy0 * 0.625f); atomicAdd(a + l4.y * TCELLS, wy0 * 0.875f);
                    atomicAdd(a + l4.z * TCELLS, wy0 * 0.875f); atomicAdd(a + l4.w * TCELLS, wy0 * 0.625f); }
                if (bp) { float* a = &A[rb + rxp];
                    atomicAdd(a + l4.z * TCELLS, wy0 * 0.125f); atomicAdd(a + l4.w * TCELLS, wy0 * 0.375f); }
            }
            if (r1) {
                int rb = (ry + 1) * TC;
                if (bm) { float* a = &A[rb + rxm];
                    atomicAdd(a + l4.x * TCELLS, wy1 * 0.375f); atomicAdd(a + l4.y * TCELLS, wy1 * 0.125f); }
                if (b0) { float* a = &A[rb + rx0];
                    atomicAdd(a + l4.x * TCELLS, wy1 * 0.625f); atomicAdd(a + l4.y * TCELLS, wy1 * 0.875f);
                    atomicAdd(a + l4.z * TCELLS, wy1 * 0.875f); atomicAdd(a + l4.w * TCELLS, wy1 * 0.625f); }
                if (bp) { float* a = &A[rb + rxp];
                    atomicAdd(a + l4.z * TCELLS, wy1 * 0.125f); atomicAdd(a + l4.w * TCELLS, wy1 * 0.375f); }
            }
        } else {
            int Ls[4] = {l4.x, l4.y, l4.z, l4.w};
#pragma unroll
            for (int j = 0; j < 4; j++) {
                int w = (q << 2) + j;
                int x0; float wx0, wx1;
                taps(w, LW - 1, x0, wx0, wx1);
                int rxa = x0 - X0, rxb = rxa + 1;
                int L = Ls[j];
                if (r0) {
                    int rb = ry * TC;
                    if ((unsigned)rxa < (unsigned)TC) atomicAdd(&A[L * TCELLS + rb + rxa], wy0 * wx0);
                    if ((unsigned)rxb < (unsigned)TC) atomicAdd(&A[L * TCELLS + rb + rxb], wy0 * wx1);
                }
                if (r1) {
                    int rb = (ry + 1) * TC;
                    if ((unsigned)rxa < (unsigned)TC) atomicAdd(&A[L * TCELLS + rb + rxa], wy1 * wx0);
                    if ((unsigned)rxb < (unsigned)TC) atomicAdd(&A[L * TCELLS + rb + rxb], wy1 * wx1);
                }
            }
        }
    };
    process(hA, qA, LA);
    if (vB) process(hB, qB, LB);
    __syncthreads();

    // ---- contract: thread (cc, cy) does row cy of channel cc ----
    {
        float ev_[8] = {ev0.x, ev0.y, ev0.z, ev0.w, ev1.x, ev1.y, ev1.z, ev1.w};
        float acc[NCLS];
#pragma unroll
        for (int k = 0; k < NCLS; k++) acc[k] = 0.f;
        int base = cy * TC;
#pragma unroll
        for (int cx = 0; cx < 8; cx++) {
            float e = ev_[cx];
            const float* Ac = &A[base + cx];
#pragma unroll
            for (int k = 0; k < NCLS; k++) acc[k] = fmaf(Ac[k * TCELLS], e, acc[k]);
        }
#pragma unroll
        for (int k = 0; k < NCLS; k++) {
            acc[k] += __shfl_xor(acc[k], 1);
            acc[k] += __shfl_xor(acc[k], 2);
            acc[k] += __shfl_xor(acc[k], 4);
        }
        if (cy == 0) {
#pragma unroll
            for (int k = 0; k < NCLS; k++) cs_l[k * CCH + cc] = acc[k];
        }
    }
    if (tid < 8 * NCLS) {
        int g8 = tid / NCLS, k = tid - g8 * NCLS;
        float s = 0.f;
#pragma unroll
        for (int j = 0; j < 8; j++) s += A[k * TCELLS + g8 * 8 + j];
        tmpc[k * 8 + g8] = s;
    }
    __syncthreads();

    float* Ps = P_sum + (size_t)(n * NTILE + tile) * NSLOT;
    if (tid < NSLOT / 4) ((float4*)Ps)[tid] = ((const float4*)cs_l)[tid];
    if (tid < NCLS) {
        float s = 0.f;
#pragma unroll
        for (int g8 = 0; g8 < 8; g8++) s += tmpc[tid * 8 + g8];
        P_cnt[(size_t)(n * NTILE + tile) * NCLS + tid] = s;
    }

    // ---- ticket; last block per image finalizes ----
    __threadfence();
    if (tid == 0) sdone = atomicAdd(&Cnt[n], 1u);
    __syncthreads();
    if (sdone != NTILE - 1) return;
    __threadfence();

    if (tid < NSLOT / 4) {
        const float4* pb = (const float4*)(P_sum + (size_t)n * NTILE * NSLOT) + tid;
        double ax = 0, ay = 0, az = 0, aw = 0, bx = 0, by = 0, bz = 0, bw = 0;
        for (int t = 0; t < NTILE; t += 2) {
            float4 v0 = pb[(size_t)t * (NSLOT / 4)];
            float4 v1 = pb[(size_t)(t + 1) * (NSLOT / 4)];
            ax += v0.x; ay += v0.y; az += v0.z; aw += v0.w;
            bx += v1.x; by += v1.y; bz += v1.z; bw += v1.w;
        }
        int idx = tid * 4, k = idx >> 5, c = idx & 31;
        cs_d[k * 33 + c] = ax + bx; cs_d[k * 33 + c + 1] = ay + by;
        cs_d[k * 33 + c + 2] = az + bz; cs_d[k * 33 + c + 3] = aw + bw;
    }
    if (tid < 8 * NCLS) {
        int g = tid / NCLS, k = tid - g * NCLS;
        const float* p1 = P_cnt + ((size_t)n * NTILE + g * 32) * NCLS + k;
        double s1 = 0.0;
#pragma unroll 4
        for (int j = 0; j < 32; j++) s1 += p1[j * NCLS];
        rk1[k * 9 + g] = s1;
    }
    if (tid < 4 * NCLS) {
        int g = tid / NCLS, k = tid - g * NCLS;
        const float* p2 = P_S2 + ((size_t)n * NBAND + g * 16) * NCLS + k;
        double s2 = 0.0;
#pragma unroll 4
        for (int j = 0; j < 16; j++) s2 += p2[j * NCLS];
        rk2[k * 5 + g] = s2;
    }
    __syncthreads();
    if (tid < NCLS) {
        double s1 = 0.0, s2 = 0.0;
#pragma unroll
        for (int g = 0; g < 8; g++) s1 += rk1[tid * 9 + g];
#pragma unroll
        for (int g = 0; g < 4; g++) s2 += rk2[tid * 5 + g];
        cnt_d[tid] = s1; s2_d[tid] = s2;
    }
    __syncthreads();
    for (int idx = tid; idx < NSLOT; idx += 256) {
        int k = idx >> 5, c = idx & 31;
        m_d[k * 33 + c] = cs_d[k * 33 + c] / (cnt_d[k] + 1.0);
    }
    __syncthreads();
    double vi = 0.0, fg = 0.0;
    if (tid >= 1 && tid < NCLS && cnt_d[tid] > 0.0) {
        fg = 1.0;
        double dot = 0.0, mm = 0.0;
        for (int c = 0; c < CCH; c++) {
            double mv = m_d[tid * 33 + c];
            dot += mv * cs_d[tid * 33 + c];
            mm += mv * mv;
        }
        vi = (s2_d[tid] - 2.0 * dot + cnt_d[tid] * mm) * 0.03125 / (cnt_d[tid] + 1.0);
    }
    if (tid < 64) {
#pragma unroll
        for (int s_ = 32; s_ >= 1; s_ >>= 1) { vi += __shfl_xor(vi, s_); fg += __shfl_xor(fg, s_); }
        if (tid == 0) { sIntra = vi; sNfg = fg; }
    }
    double ve = 0.0;
    for (int t2 = tid; t2 < 324; t2 += 256) {
        int j = 1 + t2 / 18, k = 1 + t2 % 18;
        if (cnt_d[j] > 0.0 && cnt_d[k] > 0.0) {
            double s = 0.0;
            for (int c = 0; c < CCH; c++) {
                double d = m_d[j * 33 + c] - m_d[k * 33 + c];
                s += d * d;
            }
            ve += s * 0.03125;
        }
    }
#pragma unroll
    for (int s_ = 32; s_ >= 1; s_ >>= 1) ve += __shfl_xor(ve, s_);
    if ((tid & 63) == 0) wpart[tid >> 6] = ve;
    __syncthreads();
    if (tid == 0) {
        double inter = wpart[0] + wpart[1] + wpart[2] + wpart[3];
        out[n] = (float)(sIntra / sNfg - inter / (sNfg * sNfg));
    }
}

extern "C" void kernel_launch(void* const* d_in, const int* in_sizes, int n_in,
                              void* d_out, int out_size, void* d_ws, size_t ws_size,
                              hipStream_t stream) {
    const float* E = (const float*)d_in[0];   // (4,32,128,128) fp32
    const int* lab = (const int*)d_in[1];     // (4,512,512) int
    float* out = (float*)d_out;               // (4,) fp32

    float* P_sum = (float*)d_ws;                             // 4*256*608 floats
    float* P_cnt = P_sum + (size_t)NIMG * NTILE * NSLOT;     // 4*256*19
    float* P_S2  = P_cnt + (size_t)NIMG * NTILE * NCLS;      // 4*64*19
    unsigned int* Cnt = (unsigned int*)(P_S2 + (size_t)NIMG * NBAND * NCLS);
    // P_* fully overwritten every call; Cnt zeroed by k_a block (0,0)

    k_a<<<dim3(NBAND, NIMG), dim3(512), 0, stream>>>(E, lab, P_S2, Cnt);
    k_b<<<dim3(NTILE, NIMG), dim3(256), 0, stream>>>(E, lab, P_sum, P_cnt, P_S2, Cnt, out);
}

// Round 8
// 123.140 us; speedup vs baseline: 2.0666x; 2.0666x over previous
//
#include <hip/hip_runtime.h>

#define NIMG 4
#define NCLS 19
#define CCH  32
#define LH   128
#define LW   128
#define HH   512
#define WW   512
#define HWQ  (LH*LW)    // 16384 low-res pixels
#define HWP  (HH*WW)    // 262144 hi-res pixels

// k_field tiling: each block OWNS a disjoint TRxTC low-res region
#define TR 8
#define TC 16
#define NTX (LW/TC)       // 8
#define NTY (LH/TR)       // 16
#define NTILE (NTY*NTX)   // 128 blocks per image
#define TCELLS (TR*TC)    // 128
#define HALO_R (TR*4+4)   // 36
#define HALO_C (TC*4+4)   // 68

// Bilinear taps for 128 -> 512, half-pixel convention. Edge taps shifted to a
// valid (b, b+1) pair with weights {1,0}/{0,1} (exact dyadic, same math).
__device__ __forceinline__ void taps(int v, int lim, int& i0, float& w0, float& w1) {
    int r = v & 3;
    int b = (v >> 2) + ((r < 2) ? -1 : 0);
    float f = 0.125f + 0.25f * (float)((r + 2) & 3);   // r: 0->.625 1->.875 2->.125 3->.375
    w0 = 1.f - f; w1 = f;
    if (b < 0)           { b = 0;       w0 = 1.f; w1 = 0.f; }
    else if (b >= lim)   { b = lim - 1; w0 = 0.f; w1 = 1.f; }
    i0 = b;
}

// K0: pre-summed Gram planes (over all 32 ch):
//   G[n][0]=<E,E>  G[n][1]=<E(y,x),E(y,x+1)>  G[n][2]=<E(y,x),E(y+1,x)>
//   G[n][3]=<E(y,x),E(y+1,x+1)> + <E(y,x+1),E(y+1,x)>
__global__ __launch_bounds__(256) void k_gram(const float* __restrict__ E,
        float* __restrict__ G) {
    int n = blockIdx.y, rp = blockIdx.x;
    int tid = threadIdx.x;
    int x = tid & 127, dy = tid >> 7;
    int y = rp * 2 + dy;
    int yn = (y < LH - 1) ? y + 1 : y;
    int xn = (x < LW - 1) ? x + 1 : x;
    bool fix = ((x & 63) == 63);             // wave edge: shfl_down(1) invalid
    const float* base = E + (size_t)n * CCH * HWQ;
    const float* Ea = base + y * LW + x;
    const float* Eb = base + yn * LW + x;
    const float* Eax = base + y * LW + xn;
    const float* Ebx = base + yn * LW + xn;
    float gs = 0.f, gh = 0.f, gv = 0.f, gda = 0.f;
#pragma unroll 8
    for (int c = 0; c < CCH; c++) {
        float a = Ea[(size_t)c * HWQ];
        float b = Eb[(size_t)c * HWQ];
        float ar = __shfl_down(a, 1);
        float br = __shfl_down(b, 1);
        if (fix) { ar = Eax[(size_t)c * HWQ]; br = Ebx[(size_t)c * HWQ]; }
        gs = fmaf(a, a, gs);
        gh = fmaf(a, ar, gh);
        gv = fmaf(a, b, gv);
        gda = fmaf(a, br, fmaf(ar, b, gda));
    }
    float* Gp = G + (size_t)n * 4 * HWQ + y * LW + x;
    Gp[0] = gs; Gp[HWQ] = gh; Gp[2 * HWQ] = gv; Gp[3 * HWQ] = gda;
}

// K1: per-tile A-field in LDS + fused contract + per-pixel S2 via Gram planes.
//   P_sum[n][tile][k][c] = sum_{cells} A[k][cell] * E[c][cell]
//   P_cnt[n][tile][k]    = sum_{cells} A[k][cell]
//   P_S2 [n][tile][k]    = sum_{owned pixels of class k} ||v_p||^2
__global__ __launch_bounds__(256) void k_field(const float* __restrict__ E,
        const int* __restrict__ lab, const float* __restrict__ G,
        float* __restrict__ P_sum, float* __restrict__ P_cnt, float* __restrict__ P_S2) {
    int tile = blockIdx.x, n = blockIdx.y;
    int ty = tile >> 3, tx = tile & 7;          // NTX=8
    int Y0 = ty * TR, X0 = tx * TC;
    __shared__ float A[TCELLS * NCLS];          // [cell][k], stride 19
    __shared__ float red[8 * NCLS * CCH];       // [g][k][c] contract partials
    __shared__ float Gt[4 * 180];               // planes: Gs, Gh, Gv, Gda (tile+ring)
    __shared__ float S2b[NCLS];
    int tid = threadIdx.x;
    for (int i = tid; i < TCELLS * NCLS; i += 256) A[i] = 0.f;
    if (tid < NCLS) S2b[tid] = 0.f;

    // stage Gram tile (rows Y0-1..Y0+8, cols X0-1..X0+16; pre-summed planes)
    const float* Gn = G + (size_t)n * 4 * HWQ;
    for (int i = tid; i < 4 * 180; i += 256) {
        int p = i / 180, r = i % 180, gy = r / 18, gx = r % 18;
        int yy = Y0 - 1 + gy; yy = yy < 0 ? 0 : (yy > LH - 1 ? LH - 1 : yy);
        int xx = X0 - 1 + gx; xx = xx < 0 ? 0 : (xx > LW - 1 ? LW - 1 : xx);
        Gt[i] = Gn[(size_t)p * HWQ + yy * LW + xx];
    }
    __syncthreads();

    // halo pass: A-field taps (all halo pixels) + S2 (owned pixels only)
    const int* ln = lab + (size_t)n * HWP;
    int h_lo = Y0 * 4 - 2, w_lo = X0 * 4 - 2;
    for (int i = tid; i < HALO_R * HALO_C; i += 256) {
        int hr = i / HALO_C, wc = i - hr * HALO_C;
        int h = h_lo + hr, w = w_lo + wc;
        if (h < 0 || h >= HH || w < 0 || w >= WW) continue;
        int L = ln[h * WW + w];
        int y0, x0; float wy0, wy1, wx0, wx1;
        taps(h, LH - 1, y0, wy0, wy1);
        taps(w, LW - 1, x0, wx0, wx1);
        int ry = y0 - Y0, rx = x0 - X0;
        if (ry >= 0 && ry < TR) {
            if (rx >= 0 && rx < TC)         atomicAdd(&A[(ry * TC + rx) * NCLS + L], wy0 * wx0);
            if (rx + 1 >= 0 && rx + 1 < TC) atomicAdd(&A[(ry * TC + rx + 1) * NCLS + L], wy0 * wx1);
        }
        if (ry + 1 >= 0 && ry + 1 < TR) {
            if (rx >= 0 && rx < TC)         atomicAdd(&A[((ry + 1) * TC + rx) * NCLS + L], wy1 * wx0);
            if (rx + 1 >= 0 && rx + 1 < TC) atomicAdd(&A[((ry + 1) * TC + rx + 1) * NCLS + L], wy1 * wx1);
        }
        if (h >= Y0 * 4 && h < Y0 * 4 + TR * 4 && w >= X0 * 4 && w < X0 * 4 + TC * 4) {
            int gy = y0 - (Y0 - 1), gx = x0 - (X0 - 1);
            int g00 = gy * 18 + gx;
            float u0 = wy0 * wy0, u1 = wy1 * wy1, u2 = wy0 * wy1;
            float s0 = wx0 * wx0, s1 = wx1 * wx1, s2 = wx0 * wx1;
            float d2 =
                u0 * (s0 * Gt[g00]      + s1 * Gt[g00 + 1]  + 2.f * s2 * Gt[180 + g00])
              + u1 * (s0 * Gt[g00 + 18] + s1 * Gt[g00 + 19] + 2.f * s2 * Gt[180 + g00 + 18])
              + 2.f * u2 * (s0 * Gt[360 + g00] + s1 * Gt[360 + g00 + 1] + s2 * Gt[540 + g00]);
            atomicAdd(&S2b[L], d2);
        }
    }
    __syncthreads();

    // fused contract: thread (g,c); A reads are (half-)wave-uniform broadcasts
    int g = tid >> 5, c = tid & 31;
    const float* Ec = E + ((size_t)n * CCH + c) * HWQ;
    float acc[NCLS];
#pragma unroll
    for (int k = 0; k < NCLS; k++) acc[k] = 0.f;
#pragma unroll
    for (int j = 0; j < TCELLS / 8; j++) {
        int cell = g * (TCELLS / 8) + j;
        int cy = cell >> 4, cx = cell & 15;     // TC=16
        float e = Ec[(Y0 + cy) * LW + (X0 + cx)];
        const float* Ar = &A[cell * NCLS];
#pragma unroll
        for (int k = 0; k < NCLS; k++) acc[k] = fmaf(Ar[k], e, acc[k]);
    }
#pragma unroll
    for (int k = 0; k < NCLS; k++) red[(g * NCLS + k) * CCH + c] = acc[k];
    __syncthreads();

    float* Ps = P_sum + (size_t)(n * NTILE + tile) * (NCLS * CCH);
    for (int idx = tid; idx < NCLS * CCH; idx += 256) {
        float s = 0.f;
#pragma unroll
        for (int gg = 0; gg < 8; gg++) s += red[gg * NCLS * CCH + idx];
        Ps[idx] = s;
    }
    if (tid < NCLS) {
        float s = 0.f;
        for (int cell = 0; cell < TCELLS; cell++) s += A[cell * NCLS + tid];
        P_cnt[(size_t)(n * NTILE + tile) * NCLS + tid] = s;
        P_S2[(size_t)(n * NTILE + tile) * NCLS + tid] = S2b[tid];
    }
}

// K3: reduce partials, intra via S2 - 2 m.s + cnt |m|^2, inter pairwise, output
__global__ __launch_bounds__(384) void k_final(const float* __restrict__ P_sum,
        const float* __restrict__ P_cnt, const float* __restrict__ P_S2,
        float* __restrict__ out) {
    int n = blockIdx.x, t = threadIdx.x;
    __shared__ float csum[NCLS * 33];   // stride-33 pad
    __shared__ float m[NCLS * 33];
    __shared__ float cnt[NCLS];
    __shared__ float S2[NCLS];
    __shared__ float rk1[NCLS * 17];
    __shared__ float rk2[NCLS * 17];
    __shared__ float sIntra, sNfg, sInter;

    if (t == 0) sInter = 0.f;
    if (t < 304) {                       // 19 classes x 16 groups, 8 tiles each
        int k = t >> 4, gg = t & 15;
        const float* p1 = P_cnt + ((size_t)n * NTILE + gg * 8) * NCLS + k;
        const float* p2 = P_S2  + ((size_t)n * NTILE + gg * 8) * NCLS + k;
        float s1 = 0.f, s2 = 0.f;
#pragma unroll
        for (int j = 0; j < 8; j++) { s1 += p1[j * NCLS]; s2 += p2[j * NCLS]; }
        rk1[k * 17 + gg] = s1; rk2[k * 17 + gg] = s2;
    }
    for (int idx = t; idx < NCLS * CCH; idx += 384) {
        float s = 0.f;
        const float* p = P_sum + (size_t)n * NTILE * NCLS * CCH + idx;
        for (int b = 0; b < NTILE; b++) s += p[b * NCLS * CCH];
        csum[(idx >> 5) * 33 + (idx & 31)] = s;
    }
    __syncthreads();
    if (t < NCLS) {
        float s1 = 0.f, s2 = 0.f;
        for (int gg = 0; gg < 16; gg++) { s1 += rk1[t * 17 + gg]; s2 += rk2[t * 17 + gg]; }
        cnt[t] = s1; S2[t] = s2;
    }
    __syncthreads();
    for (int idx = t; idx < NCLS * CCH; idx += 384) {
        int k = idx >> 5, c = idx & 31;
        m[k * 33 + c] = csum[k * 33 + c] / (cnt[k] + 1.f);
    }
    __syncthreads();

    // intra + n_fg (all of t<19 sits in wave 0)
    float vi = 0.f, fg = 0.f;
    if (t >= 1 && t < NCLS && cnt[t] > 0.f) {
        fg = 1.f;
        float dot = 0.f, mm = 0.f;
        for (int c = 0; c < CCH; c++) {
            float mv = m[t * 33 + c];
            dot = fmaf(mv, csum[t * 33 + c], dot);
            mm = fmaf(mv, mv, mm);
        }
        vi = (S2[t] - 2.f * dot + cnt[t] * mm) * (1.f / 32.f) / (cnt[t] + 1.f);
    }
#pragma unroll
    for (int s_ = 32; s_ >= 1; s_ >>= 1) { vi += __shfl_xor(vi, s_); fg += __shfl_xor(fg, s_); }
    if (t == 0) { sIntra = vi; sNfg = fg; }

    // inter: 18x18 foreground pairs
    float ve = 0.f;
    if (t < 324) {
        int j = 1 + t / 18, k = 1 + t % 18;
        if (cnt[j] > 0.f && cnt[k] > 0.f) {
            float s = 0.f;
            for (int c = 0; c < CCH; c++) {
                float d = m[j * 33 + c] - m[k * 33 + c];
                s = fmaf(d, d, s);
            }
            ve = s * (1.f / 32.f);
        }
    }
#pragma unroll
    for (int s_ = 32; s_ >= 1; s_ >>= 1) ve += __shfl_xor(ve, s_);
    if ((t & 63) == 0) atomicAdd(&sInter, ve);
    __syncthreads();
    if (t == 0) out[n] = sIntra / sNfg - sInter / (sNfg * sNfg);
}

extern "C" void kernel_launch(void* const* d_in, const int* in_sizes, int n_in,
                              void* d_out, int out_size, void* d_ws, size_t ws_size,
                              hipStream_t stream) {
    const float* E = (const float*)d_in[0];   // (4,32,128,128) fp32
    const int* lab = (const int*)d_in[1];     // (4,512,512) int
    float* out = (float*)d_out;               // (4,) fp32

    float* ws = (float*)d_ws;
    float* P_sum = ws;                                        // 4*128*608
    float* P_cnt = P_sum + (size_t)NIMG * NTILE * NCLS * CCH; // 4*128*19
    float* P_S2  = P_cnt + (size_t)NIMG * NTILE * NCLS;       // 4*128*19
    float* G     = P_S2  + (size_t)NIMG * NTILE * NCLS;       // 4*4*HWQ (256 KB)
    // all partial slots are fully overwritten every call -> no memset needed

    k_gram <<<dim3(64, NIMG),    dim3(256), 0, stream>>>(E, G);
    k_field<<<dim3(NTILE, NIMG), dim3(256), 0, stream>>>(E, lab, G, P_sum, P_cnt, P_S2);
    k_final<<<dim3(NIMG),        dim3(384), 0, stream>>>(P_sum, P_cnt, P_S2, out);
}